// Round 4
// baseline (580.071 us; speedup 1.0000x reference)
//
#include <hip/hip_runtime.h>
#include <cstdint>

#define NEXP 8
#define TOPK 2
#define NTOK 4096
#define NSLOT (NTOK * TOPK)   // 8192
#define CAP 1280              // expert capacity
#define DM 2048               // d_model == hidden
#define EC (NEXP * CAP)       // 10240 binned rows
#define KT 32                 // K tiles: 2048 / 64

typedef __bf16 bf16x8 __attribute__((ext_vector_type(8)));
typedef __bf16 bf16x4 __attribute__((ext_vector_type(4)));
typedef float  f32x4  __attribute__((ext_vector_type(4)));

typedef const void __attribute__((address_space(1))) gvoid;
typedef void __attribute__((address_space(3))) lvoid;

__device__ __forceinline__ void gld16(const void* g, void* l) {
  __builtin_amdgcn_global_load_lds((gvoid*)(uintptr_t)g, (lvoid*)(uintptr_t)l,
                                   16, 0, 0);
}

// ---------------------------------------------------------------- routing
__global__ void route_k(const int* __restrict__ eidx, int* __restrict__ row_token,
                        int* __restrict__ slot_dest, int* __restrict__ mcount,
                        float* __restrict__ out) {
  __shared__ int lh[256][NEXP];
  int tid = threadIdx.x;
  for (int i = tid; i < EC; i += 256) row_token[i] = -1;
#pragma unroll
  for (int e = 0; e < NEXP; ++e) lh[tid][e] = 0;
  __syncthreads();
  int base = tid * 32;
  for (int j = 0; j < 32; ++j) lh[tid][eidx[base + j]]++;
  __syncthreads();
  if (tid < NEXP) {
    int run = 0;
    for (int i = 0; i < 256; ++i) { int t = lh[i][tid]; lh[i][tid] = run; run += t; }
    mcount[tid] = run < CAP ? run : CAP;
    out[(size_t)NTOK * DM + tid] = (float)run;
  }
  __syncthreads();
  for (int j = 0; j < 32; ++j) {
    int t = base + j;
    int e = eidx[t];
    int r = lh[tid][e]++;
    if (r < CAP) { int dst = e * CAP + r; slot_dest[t] = dst; row_token[dst] = t >> 1; }
    else slot_dest[t] = -1;
  }
}

// ------------------------------------------------------- gather + fp32->bf16
__global__ void gather_k(const float* __restrict__ x, const int* __restrict__ row_token,
                         __bf16* __restrict__ xg) {
  int r = blockIdx.x;
  int c = threadIdx.x * 8;
  int tok = row_token[r];
  bf16x8 o;
  if (tok >= 0) {
    const float* src = x + (size_t)tok * DM + c;
    float4 a = *(const float4*)src;
    float4 b = *(const float4*)(src + 4);
    o[0] = (__bf16)a.x; o[1] = (__bf16)a.y; o[2] = (__bf16)a.z; o[3] = (__bf16)a.w;
    o[4] = (__bf16)b.x; o[5] = (__bf16)b.y; o[6] = (__bf16)b.z; o[7] = (__bf16)b.w;
  } else {
#pragma unroll
    for (int j = 0; j < 8; ++j) o[j] = (__bf16)0.f;
  }
  *(bf16x8*)(xg + (size_t)r * DM + c) = o;
}

// --------------------------------------- fp32 [E][K][N] -> bf16 [E][N][K]
__global__ void transT_k(const float* __restrict__ w, __bf16* __restrict__ wT) {
  __shared__ __bf16 t[64][65];
  int e = blockIdx.z;
  int n0 = blockIdx.x * 64, k0 = blockIdx.y * 64;
  const float* src = w + ((size_t)e << 22) + (size_t)k0 * DM + n0;
  __bf16* dst = wT + ((size_t)e << 22) + (size_t)n0 * DM + k0;
  int c = threadIdx.x & 63, r4 = threadIdx.x >> 6;
#pragma unroll
  for (int p = 0; p < 16; ++p) {
    int r = p * 4 + r4;
    t[r][c] = (__bf16)src[(size_t)r * DM + c];
  }
  __syncthreads();
  int j = threadIdx.x & 15, rr0 = threadIdx.x >> 4;
#pragma unroll
  for (int q = 0; q < 4; ++q) {
    int rr = q * 16 + rr0;
    bf16x4 v;
    v[0] = t[4 * j + 0][rr];
    v[1] = t[4 * j + 1][rr];
    v[2] = t[4 * j + 2][rr];
    v[3] = t[4 * j + 3][rr];
    *(bf16x4*)(dst + (size_t)rr * DM + 4 * j) = v;
  }
}

// ------------------------------------------------------------------- GEMM
// C[rows,N] = A[rows,K] * BT[N,K]^T per expert. BM=BN=256, BK=64.
// 512 thr = 8 waves (2M x 4N), per-wave 128x64 C, acc[8][4].
// 4 phases per K-tile (m201-style): each phase {ds_read frags; (stage);
// barrier; lgkmcnt(0); sched_barrier; setprio1; 16 MFMA; setprio0; barrier}.
// B-frags register-reused across 2 phases (24 reads/tile/wave).
// Per CU per tile: 512 MFMA ~2660cy vs LDS ~750cy -> MFMA-dominated.
// Buffers: tile t in buf t&1; t+1 staged during t's P0 into buf (t&1)^1,
// whose readers (t-1) finished behind t-1's last lgkmcnt(0)+barrier.
// vmcnt(0) at tile top: t's loads issued 4 phases (~2600cy) ago -> free.
// LDS rows 128B, 16B-chunk ^= row&7 swizzle (0 conflicts, R1-proven),
// staged with inverse-swizzled GLOBAL source + linear LDS dest (rule #21).
template<bool SWI>
__global__ __launch_bounds__(512, 2)
void gemm256_k(const __bf16* __restrict__ A0, const __bf16* __restrict__ BT,
               __bf16* C, __bf16* U, const int* __restrict__ mcount) {
  int e = blockIdx.z, mt = blockIdx.y, nt = blockIdx.x;
  if (mt * 256 >= mcount[e]) return;

  __shared__ __align__(16) char smem[128 * 1024];
  char* lA = smem;                    // 2 x 32KB (256 rows x 128B)
  char* lB = smem + 65536;            // 2 x 32KB (256 rows x 128B)

  int tid = threadIdx.x, w = tid >> 6, l = tid & 63;
  int wr = w >> 2, wc = w & 3;        // 2M x 4N wave grid
  int lr = l & 15, kg = l >> 4;

  const char* gA = (const char*)(A0 + (size_t)(e * CAP + mt * 256) * DM);
  const char* gB = (const char*)(BT + ((size_t)e * DM + (size_t)nt * 256) * DM);

  int sr = tid >> 3, scs = (tid & 7) ^ ((tid >> 3) & 7);

  // one call: 512 lanes x 16B = 64 rows x 128B, LDS linear
  auto stA = [&](int t, int d, int s) {
    gld16(gA + (size_t)(s * 64 + sr) * 4096 + (size_t)t * 128 + scs * 16,
          lA + d * 32768 + s * 8192 + w * 1024);
  };
  auto stB = [&](int t, int d, int s) {
    gld16(gB + (size_t)(s * 64 + sr) * 4096 + (size_t)t * 128 + scs * 16,
          lB + d * 32768 + s * 8192 + w * 1024);
  };

  // fragment readers (swizzled)
  auto rdA = [&](bf16x8* dst, int d, int mh, int ks) {
#pragma unroll
    for (int i = 0; i < 4; ++i) {
      int r = wr * 128 + (mh * 4 + i) * 16 + lr;
      int c = ks * 4 + kg;
      dst[i] = *(const bf16x8*)(lA + d * 32768 + r * 128 + ((c ^ (r & 7)) * 16));
    }
  };
  auto rdB = [&](bf16x8* dst, int d, int ks) {
#pragma unroll
    for (int n = 0; n < 4; ++n) {
      int r = wc * 64 + n * 16 + lr;
      int c = ks * 4 + kg;
      dst[n] = *(const bf16x8*)(lB + d * 32768 + r * 128 + ((c ^ (r & 7)) * 16));
    }
  };

  // prologue: tile 0 -> buf 0 (8 loads)
#pragma unroll
  for (int s = 0; s < 4; ++s) { stA(0, 0, s); stB(0, 0, s); }

  f32x4 acc[8][4];
#pragma unroll
  for (int m = 0; m < 8; ++m)
#pragma unroll
    for (int n = 0; n < 4; ++n)
#pragma unroll
      for (int j = 0; j < 4; ++j) acc[m][n][j] = 0.f;

#define PHASE_PRE                                          \
  __builtin_amdgcn_s_barrier();                            \
  asm volatile("s_waitcnt lgkmcnt(0)" ::: "memory");       \
  __builtin_amdgcn_sched_barrier(0);                       \
  __builtin_amdgcn_s_setprio(1);
#define PHASE_POST                                         \
  __builtin_amdgcn_s_setprio(0);                           \
  __builtin_amdgcn_s_barrier();
#define MFMA16(AF, BF, MH)                                 \
  _Pragma("unroll")                                        \
  for (int i = 0; i < 4; ++i)                              \
    _Pragma("unroll")                                      \
    for (int n = 0; n < 4; ++n)                            \
      acc[MH * 4 + i][n] = __builtin_amdgcn_mfma_f32_16x16x32_bf16( \
          AF[i], BF[n], acc[MH * 4 + i][n], 0, 0, 0);

#pragma unroll 1
  for (int t = 0; t < KT; ++t) {
    int d = t & 1;
    asm volatile("s_waitcnt vmcnt(0)" ::: "memory");   // tile t resident
    __builtin_amdgcn_s_barrier();

    bf16x8 a[4], b0[4], b1[4];
    // ---- P0: m0-3 x ks0; stage tile t+1 -> buf d^1
    rdA(a, d, 0, 0);
    rdB(b0, d, 0);
    if (t + 1 < KT) {
#pragma unroll
      for (int s = 0; s < 4; ++s) { stA(t + 1, d ^ 1, s); stB(t + 1, d ^ 1, s); }
    }
    PHASE_PRE; MFMA16(a, b0, 0); PHASE_POST;

    // ---- P1: m4-7 x ks0 (b0 reused from regs)
    rdA(a, d, 1, 0);
    PHASE_PRE; MFMA16(a, b0, 1); PHASE_POST;

    // ---- P2: m0-3 x ks1
    rdA(a, d, 0, 1);
    rdB(b1, d, 1);
    PHASE_PRE; MFMA16(a, b1, 0); PHASE_POST;

    // ---- P3: m4-7 x ks1 (b1 reused)
    rdA(a, d, 1, 1);
    PHASE_PRE; MFMA16(a, b1, 1); PHASE_POST;
  }

  // ---- epilogue: C/D layout col=lane&15, row=(lane>>4)*4+j [m89-verified]
  int rg = l >> 4;
#pragma unroll
  for (int m = 0; m < 8; ++m)
#pragma unroll
    for (int n = 0; n < 4; ++n)
#pragma unroll
      for (int j = 0; j < 4; ++j) {
        int row = e * CAP + mt * 256 + wr * 128 + m * 16 + rg * 4 + j;
        int col = nt * 256 + wc * 64 + n * 16 + lr;
        size_t off = (size_t)row * DM + col;
        float v = acc[m][n][j];
        if constexpr (SWI) {
          float u = (float)U[off];
          float s = u / (1.f + __expf(-u));
          C[off] = (__bf16)(s * v);            // h = silu(u) * v, in place
        } else {
          C[off] = (__bf16)v;
        }
      }
#undef PHASE_PRE
#undef PHASE_POST
#undef MFMA16
}

// --------------------------------------------- combine: y[tok] = sum w * ye
__global__ void combine_k(const __bf16* __restrict__ ye, const int* __restrict__ slot_dest,
                          const float* __restrict__ ew, float* __restrict__ out) {
  int tok = blockIdx.x;
  int c = threadIdx.x * 8;
  int d0 = slot_dest[2 * tok], d1 = slot_dest[2 * tok + 1];
  float w0 = ew[2 * tok], w1 = ew[2 * tok + 1];
  float r[8];
#pragma unroll
  for (int j = 0; j < 8; ++j) r[j] = 0.f;
  if (d0 >= 0) {
    bf16x8 y0 = *(const bf16x8*)(ye + (size_t)d0 * DM + c);
#pragma unroll
    for (int j = 0; j < 8; ++j) r[j] += w0 * (float)y0[j];
  }
  if (d1 >= 0) {
    bf16x8 y1 = *(const bf16x8*)(ye + (size_t)d1 * DM + c);
#pragma unroll
    for (int j = 0; j < 8; ++j) r[j] += w1 * (float)y1[j];
  }
  float* dst = out + (size_t)tok * DM + c;
  float4 o0; o0.x = r[0]; o0.y = r[1]; o0.z = r[2]; o0.w = r[3];
  float4 o1; o1.x = r[4]; o1.y = r[5]; o1.z = r[6]; o1.w = r[7];
  *(float4*)dst = o0;
  *(float4*)(dst + 4) = o1;
}

extern "C" void kernel_launch(void* const* d_in, const int* in_sizes, int n_in,
                              void* d_out, int out_size, void* d_ws, size_t ws_size,
                              hipStream_t stream) {
  const float* x  = (const float*)d_in[0];
  const float* ew = (const float*)d_in[1];
  const int*   ei = (const int*)d_in[2];
  const float* w1 = (const float*)d_in[3];
  const float* w2 = (const float*)d_in[4];
  const float* w3 = (const float*)d_in[5];
  float* out = (float*)d_out;
  char* ws = (char*)d_ws;

  const size_t SZ_MAT = (size_t)EC * DM * 2;            // 41,943,040 B
  __bf16* xg = (__bf16*)ws;                             // xg, then ye
  __bf16* uB = (__bf16*)(ws + SZ_MAT);                  // u, then h
  __bf16* wT = (__bf16*)(ws + 2 * SZ_MAT);              // [8][2048][2048] bf16
  char* ints = ws + 2 * SZ_MAT + (size_t)NEXP * DM * DM * 2;
  int* row_token = (int*)ints;
  int* slot_dest = row_token + EC;
  int* mcount    = slot_dest + NSLOT;

  dim3 tgrid(32, 32, NEXP);
  dim3 ggrid(8, 5, NEXP);                               // nt(256), mt(256), e

  route_k<<<1, 256, 0, stream>>>(ei, row_token, slot_dest, mcount, out);
  gather_k<<<EC, 256, 0, stream>>>(x, row_token, xg);

  transT_k<<<tgrid, 256, 0, stream>>>(w1, wT);
  gemm256_k<false><<<ggrid, 512, 0, stream>>>(xg, wT, uB, nullptr, mcount); // u

  transT_k<<<tgrid, 256, 0, stream>>>(w3, wT);
  gemm256_k<true><<<ggrid, 512, 0, stream>>>(xg, wT, uB, uB, mcount);       // h

  transT_k<<<tgrid, 256, 0, stream>>>(w2, wT);
  gemm256_k<false><<<ggrid, 512, 0, stream>>>(uB, wT, xg, nullptr, mcount); // ye

  combine_k<<<NTOK, 256, 0, stream>>>(xg, slot_dest, ew, out);
}

// Round 5
// 570.255 us; speedup vs baseline: 1.0172x; 1.0172x over previous
//
#include <hip/hip_runtime.h>
#include <cstdint>

#define NEXP 8
#define TOPK 2
#define NTOK 4096
#define NSLOT (NTOK * TOPK)   // 8192
#define CAP 1280              // expert capacity
#define DM 2048               // d_model == hidden
#define EC (NEXP * CAP)       // 10240 binned rows
#define KT 32                 // K tiles: 2048 / 64

typedef __bf16 bf16x8 __attribute__((ext_vector_type(8)));
typedef __bf16 bf16x4 __attribute__((ext_vector_type(4)));
typedef float  f32x4  __attribute__((ext_vector_type(4)));

typedef const void __attribute__((address_space(1))) gvoid;
typedef void __attribute__((address_space(3))) lvoid;

__device__ __forceinline__ void gld16(const void* g, void* l) {
  __builtin_amdgcn_global_load_lds((gvoid*)(uintptr_t)g, (lvoid*)(uintptr_t)l,
                                   16, 0, 0);
}

// ---------------------------------------------------------------- routing
__global__ void route_k(const int* __restrict__ eidx, int* __restrict__ row_token,
                        int* __restrict__ slot_dest, int* __restrict__ mcount,
                        float* __restrict__ out) {
  __shared__ int lh[256][NEXP];
  int tid = threadIdx.x;
  for (int i = tid; i < EC; i += 256) row_token[i] = -1;
#pragma unroll
  for (int e = 0; e < NEXP; ++e) lh[tid][e] = 0;
  __syncthreads();
  int base = tid * 32;
  for (int j = 0; j < 32; ++j) lh[tid][eidx[base + j]]++;
  __syncthreads();
  if (tid < NEXP) {
    int run = 0;
    for (int i = 0; i < 256; ++i) { int t = lh[i][tid]; lh[i][tid] = run; run += t; }
    mcount[tid] = run < CAP ? run : CAP;
    out[(size_t)NTOK * DM + tid] = (float)run;
  }
  __syncthreads();
  for (int j = 0; j < 32; ++j) {
    int t = base + j;
    int e = eidx[t];
    int r = lh[tid][e]++;
    if (r < CAP) { int dst = e * CAP + r; slot_dest[t] = dst; row_token[dst] = t >> 1; }
    else slot_dest[t] = -1;
  }
}

// ------------------------------------------------------- gather + fp32->bf16
__global__ void gather_k(const float* __restrict__ x, const int* __restrict__ row_token,
                         __bf16* __restrict__ xg) {
  int r = blockIdx.x;
  int c = threadIdx.x * 8;
  int tok = row_token[r];
  bf16x8 o;
  if (tok >= 0) {
    const float* src = x + (size_t)tok * DM + c;
    float4 a = *(const float4*)src;
    float4 b = *(const float4*)(src + 4);
    o[0] = (__bf16)a.x; o[1] = (__bf16)a.y; o[2] = (__bf16)a.z; o[3] = (__bf16)a.w;
    o[4] = (__bf16)b.x; o[5] = (__bf16)b.y; o[6] = (__bf16)b.z; o[7] = (__bf16)b.w;
  } else {
#pragma unroll
    for (int j = 0; j < 8; ++j) o[j] = (__bf16)0.f;
  }
  *(bf16x8*)(xg + (size_t)r * DM + c) = o;
}

// --------------------------------------- fp32 [E][K][N] -> bf16 [E][N][K]
__global__ void transT_k(const float* __restrict__ w, __bf16* __restrict__ wT) {
  __shared__ __bf16 t[64][65];
  int e = blockIdx.z;
  int n0 = blockIdx.x * 64, k0 = blockIdx.y * 64;
  const float* src = w + ((size_t)e << 22) + (size_t)k0 * DM + n0;
  __bf16* dst = wT + ((size_t)e << 22) + (size_t)n0 * DM + k0;
  int c = threadIdx.x & 63, r4 = threadIdx.x >> 6;
#pragma unroll
  for (int p = 0; p < 16; ++p) {
    int r = p * 4 + r4;
    t[r][c] = (__bf16)src[(size_t)r * DM + c];
  }
  __syncthreads();
  int j = threadIdx.x & 15, rr0 = threadIdx.x >> 4;
#pragma unroll
  for (int q = 0; q < 4; ++q) {
    int rr = q * 16 + rr0;
    bf16x4 v;
    v[0] = t[4 * j + 0][rr];
    v[1] = t[4 * j + 1][rr];
    v[2] = t[4 * j + 2][rr];
    v[3] = t[4 * j + 3][rr];
    *(bf16x4*)(dst + (size_t)rr * DM + 4 * j) = v;
  }
}

// ------------------------------------------------------------------- GEMM
// m201-faithful 256x256x64 8-wave schedule (4 phases/K-tile, quadrant x K=64).
// Per phase: 12 ds_read_b128 (A: 4 rows x 2 chunks, B: 2 rows x 2 chunks) ->
//   [counted vmcnt] -> [stage 4 stripes of t+1] -> barrier -> lgkmcnt(0) ->
//   setprio1 -> 16 MFMA -> setprio0 -> barrier.
// Stage order for tile t+1 (issued at t.p0: v0..3 = B s0..s3; t.p1: v4..7 =
//   A s0,s2,s1,s3).  Consumption needs: p0 {B all, A s0,s2}; p1 {A s1,s3}.
// Waits: p0: vmcnt(0) BEFORE staging (drains this tile's A s1,s3, staged 3
//   phases ago -> near-free); p3: vmcnt(2) (leaves newest 2 = t+1's A s1,s3
//   in flight; guarantees v0..v5 landed for next p0).  Never drains fresh
//   loads; every consumed stripe has >=2 phases (~1600cy) of slack.
// Buffer safety: t+1 staged into buf d^1 whose readers (tile t-1) finished
//   behind t-1.p3's lgkmcnt(0) + closing barrier.
// LDS rows 128B, 16B-chunk ^= row&7 swizzle (0 conflicts, R1-proven), staged
//   with inverse-swizzled GLOBAL source + linear LDS dest (rule #21).
template<bool SWI>
__global__ __launch_bounds__(512, 2)
void gemmT_k(const __bf16* __restrict__ A0, const __bf16* __restrict__ BT,
             __bf16* C, __bf16* U, const int* __restrict__ mcount) {
  // XCD-chunked swizzle: 320 blocks, 8 XCDs x 40 -> each XCD owns one expert
  int lbid = blockIdx.x + 8 * (blockIdx.y + 5 * blockIdx.z);
  int nb = (lbid % 8) * 40 + lbid / 8;
  int nt = nb % 8, mt = (nb / 8) % 5, e = nb / 40;
  if (mt * 256 >= mcount[e]) return;

  __shared__ __align__(16) char smem[128 * 1024];
  char* lA = smem;                    // 2 bufs x 32KB (256 rows x 128B)
  char* lB = smem + 65536;            // 2 bufs x 32KB

  int tid = threadIdx.x, w = tid >> 6, l = tid & 63;
  int wr = w >> 2, wc = w & 3;        // 2M x 4N wave grid
  int lr = l & 15, kg = l >> 4;

  const char* gA = (const char*)(A0 + (size_t)(e * CAP + mt * 256) * DM);
  const char* gB = (const char*)(BT + ((size_t)e * DM + (size_t)nt * 256) * DM);

  int sr = tid >> 3, scs = (tid & 7) ^ ((tid >> 3) & 7);

  // one call: 512 lanes x 16B = one 64-row stripe (8KB), LDS linear
  auto stA = [&](int t, int d, int s) {
    gld16(gA + (size_t)(s * 64 + sr) * 4096 + (size_t)t * 128 + scs * 16,
          lA + d * 32768 + s * 8192 + w * 1024);
  };
  auto stB = [&](int t, int d, int s) {
    gld16(gB + (size_t)(s * 64 + sr) * 4096 + (size_t)t * 128 + scs * 16,
          lB + d * 32768 + s * 8192 + w * 1024);
  };

  auto rdA = [&](bf16x8* af, int d, int mh) {   // af[i*2+k], 8 reads
#pragma unroll
    for (int i = 0; i < 4; ++i)
#pragma unroll
      for (int k = 0; k < 2; ++k) {
        int r = wr * 128 + mh * 64 + i * 16 + lr;
        int c = k * 4 + kg;
        af[i * 2 + k] = *(const bf16x8*)(lA + d * 32768 + r * 128 + ((c ^ (r & 7)) * 16));
      }
  };
  auto rdB = [&](bf16x8* bf, int d, int nh) {   // bf[j*2+k], 4 reads
#pragma unroll
    for (int j = 0; j < 2; ++j)
#pragma unroll
      for (int k = 0; k < 2; ++k) {
        int r = wc * 64 + nh * 32 + j * 16 + lr;
        int c = k * 4 + kg;
        bf[j * 2 + k] = *(const bf16x8*)(lB + d * 32768 + r * 128 + ((c ^ (r & 7)) * 16));
      }
  };

  f32x4 acc[8][4];
#pragma unroll
  for (int m = 0; m < 8; ++m)
#pragma unroll
    for (int n = 0; n < 4; ++n)
#pragma unroll
      for (int j = 0; j < 4; ++j) acc[m][n][j] = 0.f;

  // prologue: tile 0 -> buf 0, order B s0..3 then A s0,s2,s1,s3
  stB(0, 0, 0); stB(0, 0, 1); stB(0, 0, 2); stB(0, 0, 3);
  stA(0, 0, 0); stA(0, 0, 2); stA(0, 0, 1); stA(0, 0, 3);
  asm volatile("s_waitcnt vmcnt(2)" ::: "memory");   // v0..v5 landed
  __builtin_amdgcn_s_barrier();

#define PHASE_TAIL(MH, NH)                                              \
  __builtin_amdgcn_sched_barrier(0);                                    \
  __builtin_amdgcn_s_barrier();                                         \
  asm volatile("s_waitcnt lgkmcnt(0)" ::: "memory");                    \
  __builtin_amdgcn_sched_barrier(0);                                    \
  __builtin_amdgcn_s_setprio(1);                                        \
  _Pragma("unroll")                                                     \
  for (int i = 0; i < 4; ++i)                                           \
    _Pragma("unroll")                                                   \
    for (int j = 0; j < 2; ++j)                                         \
      _Pragma("unroll")                                                 \
      for (int k = 0; k < 2; ++k)                                       \
        acc[MH * 4 + i][NH * 2 + j] =                                   \
            __builtin_amdgcn_mfma_f32_16x16x32_bf16(                    \
                af[i * 2 + k], bf[j * 2 + k], acc[MH * 4 + i][NH * 2 + j], 0, 0, 0); \
  __builtin_amdgcn_s_setprio(0);                                        \
  __builtin_amdgcn_s_barrier();

#pragma unroll 1
  for (int t = 0; t < KT; ++t) {
    int d = t & 1, nd = d ^ 1;
    bool st = (t + 1 < KT);
    bf16x8 af[8], bf[4];

    // ---- p0: (mh0, nh0)
    rdA(af, d, 0); rdB(bf, d, 0);
    asm volatile("s_waitcnt vmcnt(0)" ::: "memory");  // drains A s1,s3 of t (3-phase slack)
    __builtin_amdgcn_sched_barrier(0);
    if (st) { stB(t + 1, nd, 0); stB(t + 1, nd, 1); stB(t + 1, nd, 2); stB(t + 1, nd, 3); }
    PHASE_TAIL(0, 0);

    // ---- p1: (mh1, nh0)
    rdA(af, d, 1);
    if (st) { stA(t + 1, nd, 0); stA(t + 1, nd, 2); stA(t + 1, nd, 1); stA(t + 1, nd, 3); }
    PHASE_TAIL(1, 0);

    // ---- p2: (mh0, nh1)
    rdA(af, d, 0); rdB(bf, d, 1);
    PHASE_TAIL(0, 1);

    // ---- p3: (mh1, nh1)
    rdA(af, d, 1);
    asm volatile("s_waitcnt vmcnt(2)" ::: "memory");  // t+1: v0..v5 landed for next p0
    __builtin_amdgcn_sched_barrier(0);
    PHASE_TAIL(1, 1);
  }
#undef PHASE_TAIL

  // ---- epilogue: C/D layout col=lane&15, row=(lane>>4)*4+j [m89-verified]
  int rg = l >> 4;
#pragma unroll
  for (int m = 0; m < 8; ++m)
#pragma unroll
    for (int n = 0; n < 4; ++n)
#pragma unroll
      for (int j = 0; j < 4; ++j) {
        int row = e * CAP + mt * 256 + wr * 128 + m * 16 + rg * 4 + j;
        int col = nt * 256 + wc * 64 + n * 16 + lr;
        size_t off = (size_t)row * DM + col;
        float v = acc[m][n][j];
        if constexpr (SWI) {
          float u = (float)U[off];
          float s = u / (1.f + __expf(-u));
          C[off] = (__bf16)(s * v);            // h = silu(u) * v, in place
        } else {
          C[off] = (__bf16)v;
        }
      }
}

// --------------------------------------------- combine: y[tok] = sum w * ye
__global__ void combine_k(const __bf16* __restrict__ ye, const int* __restrict__ slot_dest,
                          const float* __restrict__ ew, float* __restrict__ out) {
  int tok = blockIdx.x;
  int c = threadIdx.x * 8;
  int d0 = slot_dest[2 * tok], d1 = slot_dest[2 * tok + 1];
  float w0 = ew[2 * tok], w1 = ew[2 * tok + 1];
  float r[8];
#pragma unroll
  for (int j = 0; j < 8; ++j) r[j] = 0.f;
  if (d0 >= 0) {
    bf16x8 y0 = *(const bf16x8*)(ye + (size_t)d0 * DM + c);
#pragma unroll
    for (int j = 0; j < 8; ++j) r[j] += w0 * (float)y0[j];
  }
  if (d1 >= 0) {
    bf16x8 y1 = *(const bf16x8*)(ye + (size_t)d1 * DM + c);
#pragma unroll
    for (int j = 0; j < 8; ++j) r[j] += w1 * (float)y1[j];
  }
  float* dst = out + (size_t)tok * DM + c;
  float4 o0; o0.x = r[0]; o0.y = r[1]; o0.z = r[2]; o0.w = r[3];
  float4 o1; o1.x = r[4]; o1.y = r[5]; o1.z = r[6]; o1.w = r[7];
  *(float4*)dst = o0;
  *(float4*)(dst + 4) = o1;
}

extern "C" void kernel_launch(void* const* d_in, const int* in_sizes, int n_in,
                              void* d_out, int out_size, void* d_ws, size_t ws_size,
                              hipStream_t stream) {
  const float* x  = (const float*)d_in[0];
  const float* ew = (const float*)d_in[1];
  const int*   ei = (const int*)d_in[2];
  const float* w1 = (const float*)d_in[3];
  const float* w2 = (const float*)d_in[4];
  const float* w3 = (const float*)d_in[5];
  float* out = (float*)d_out;
  char* ws = (char*)d_ws;

  const size_t SZ_MAT = (size_t)EC * DM * 2;            // 41,943,040 B
  __bf16* xg = (__bf16*)ws;                             // xg, then ye
  __bf16* uB = (__bf16*)(ws + SZ_MAT);                  // u, then h
  __bf16* wT = (__bf16*)(ws + 2 * SZ_MAT);              // [8][2048][2048] bf16
  char* ints = ws + 2 * SZ_MAT + (size_t)NEXP * DM * DM * 2;
  int* row_token = (int*)ints;
  int* slot_dest = row_token + EC;
  int* mcount    = slot_dest + NSLOT;

  dim3 tgrid(32, 32, NEXP);
  dim3 ggrid(8, 5, NEXP);                               // nt(256), mt(256), e

  route_k<<<1, 256, 0, stream>>>(ei, row_token, slot_dest, mcount, out);
  gather_k<<<EC, 256, 0, stream>>>(x, row_token, xg);

  transT_k<<<tgrid, 256, 0, stream>>>(w1, wT);
  gemmT_k<false><<<ggrid, 512, 0, stream>>>(xg, wT, uB, nullptr, mcount); // u

  transT_k<<<tgrid, 256, 0, stream>>>(w3, wT);
  gemmT_k<true><<<ggrid, 512, 0, stream>>>(xg, wT, uB, uB, mcount);       // h

  transT_k<<<tgrid, 256, 0, stream>>>(w2, wT);
  gemmT_k<false><<<ggrid, 512, 0, stream>>>(uB, wT, xg, nullptr, mcount); // ye

  combine_k<<<NTOK, 256, 0, stream>>>(xg, slot_dest, ew, out);
}

// Round 6
// 449.123 us; speedup vs baseline: 1.2916x; 1.2697x over previous
//
#include <hip/hip_runtime.h>
#include <cstdint>

#define NEXP 8
#define TOPK 2
#define NTOK 4096
#define NSLOT (NTOK * TOPK)   // 8192
#define CAP 1280              // expert capacity
#define DM 2048               // d_model == hidden
#define EC (NEXP * CAP)       // 10240 binned rows

typedef __bf16 bf16x8 __attribute__((ext_vector_type(8)));
typedef __bf16 bf16x4 __attribute__((ext_vector_type(4)));
typedef float  f32x4  __attribute__((ext_vector_type(4)));

typedef const void __attribute__((address_space(1))) gvoid;
typedef void __attribute__((address_space(3))) lvoid;

__device__ __forceinline__ void gld16(const void* g, void* l) {
  __builtin_amdgcn_global_load_lds((gvoid*)(uintptr_t)g, (lvoid*)(uintptr_t)l,
                                   16, 0, 0);
}

// ---------------------------------------------------------------- routing
__global__ void route_k(const int* __restrict__ eidx, int* __restrict__ row_token,
                        int* __restrict__ slot_dest, int* __restrict__ mcount,
                        float* __restrict__ out) {
  __shared__ int lh[256][NEXP];
  int tid = threadIdx.x;
  for (int i = tid; i < EC; i += 256) row_token[i] = -1;
#pragma unroll
  for (int e = 0; e < NEXP; ++e) lh[tid][e] = 0;
  __syncthreads();
  int base = tid * 32;
  for (int j = 0; j < 32; ++j) lh[tid][eidx[base + j]]++;
  __syncthreads();
  if (tid < NEXP) {
    int run = 0;
    for (int i = 0; i < 256; ++i) { int t = lh[i][tid]; lh[i][tid] = run; run += t; }
    mcount[tid] = run < CAP ? run : CAP;
    out[(size_t)NTOK * DM + tid] = (float)run;
  }
  __syncthreads();
  for (int j = 0; j < 32; ++j) {
    int t = base + j;
    int e = eidx[t];
    int r = lh[tid][e]++;
    if (r < CAP) { int dst = e * CAP + r; slot_dest[t] = dst; row_token[dst] = t >> 1; }
    else slot_dest[t] = -1;
  }
}

// ------------------------------------------------------- gather + fp32->bf16
__global__ void gather_k(const float* __restrict__ x, const int* __restrict__ row_token,
                         __bf16* __restrict__ xg) {
  int r = blockIdx.x;
  int c = threadIdx.x * 8;
  int tok = row_token[r];
  bf16x8 o;
  if (tok >= 0) {
    const float* src = x + (size_t)tok * DM + c;
    float4 a = *(const float4*)src;
    float4 b = *(const float4*)(src + 4);
    o[0] = (__bf16)a.x; o[1] = (__bf16)a.y; o[2] = (__bf16)a.z; o[3] = (__bf16)a.w;
    o[4] = (__bf16)b.x; o[5] = (__bf16)b.y; o[6] = (__bf16)b.z; o[7] = (__bf16)b.w;
  } else {
#pragma unroll
    for (int j = 0; j < 8; ++j) o[j] = (__bf16)0.f;
  }
  *(bf16x8*)(xg + (size_t)r * DM + c) = o;
}

// --------------------------------------- fp32 [E][K][N] -> bf16 [E][N][K]
__global__ void transT_k(const float* __restrict__ w, __bf16* __restrict__ wT) {
  __shared__ __bf16 t[64][65];
  int e = blockIdx.z;
  int n0 = blockIdx.x * 64, k0 = blockIdx.y * 64;
  const float* src = w + ((size_t)e << 22) + (size_t)k0 * DM + n0;
  __bf16* dst = wT + ((size_t)e << 22) + (size_t)n0 * DM + k0;
  int c = threadIdx.x & 63, r4 = threadIdx.x >> 6;
#pragma unroll
  for (int p = 0; p < 16; ++p) {
    int r = p * 4 + r4;
    t[r][c] = (__bf16)src[(size_t)r * DM + c];
  }
  __syncthreads();
  int j = threadIdx.x & 15, rr0 = threadIdx.x >> 4;
#pragma unroll
  for (int q = 0; q < 4; ++q) {
    int rr = q * 16 + rr0;
    bf16x4 v;
    v[0] = t[4 * j + 0][rr];
    v[1] = t[4 * j + 1][rr];
    v[2] = t[4 * j + 2][rr];
    v[3] = t[4 * j + 3][rr];
    *(bf16x4*)(dst + (size_t)rr * DM + 4 * j) = v;
  }
}

// ------------------------------------------------------------------- GEMM
// R1-exact structure (measured 107us, MfmaUtil 27.6%, 803 TF): 128x128 tile,
// BK=64, 4 waves (2x2), single LDS buffer, 2 syncthreads per K-tile,
// 2 blocks/CU. Plus: XCD-chunked block swizzle (R5-measured: FETCH 197->86MB)
// and template SWI epilogue fusion (silu(u)*v in place).
// LDS rows 128B, 16B-chunk ^= row&7 swizzle (0 conflicts, R1-proven), staged
// with inverse-swizzled GLOBAL source + linear LDS dest (rule #21).
template<bool SWI>
__global__ __launch_bounds__(256, 2)
void gemm_k(const __bf16* __restrict__ A0, const __bf16* __restrict__ BT,
            __bf16* C, __bf16* U, const int* __restrict__ mcount) {
  // XCD-chunked swizzle: 1280 blocks = 8 XCDs x 160; each XCD owns 1 expert.
  int lbid = blockIdx.x + 16 * (blockIdx.y + 10 * blockIdx.z);
  int nb = (lbid & 7) * 160 + (lbid >> 3);
  int e = nb / 160, rem = nb % 160, mt = rem >> 4, nt = rem & 15;
  int mc = mcount[e];
  if (mt * 128 >= mc) return;

  __shared__ __align__(16) char smem[128 * 64 * 2 * 2];  // A tile + B tile
  char* lA = smem;
  char* lB = smem + 128 * 64 * 2;

  int row0 = e * CAP + mt * 128;
  const char* gA = (const char*)(A0 + (size_t)row0 * DM);
  const char* gB = (const char*)(BT + ((size_t)e * DM + (size_t)nt * 128) * DM);

  int tid = threadIdx.x, w = tid >> 6, l = tid & 63;
  int wr = w >> 1, wc = w & 1;
  int sr = l >> 3;
  int sc = l & 7;

  f32x4 acc[4][4];
#pragma unroll
  for (int m = 0; m < 4; ++m)
#pragma unroll
    for (int n = 0; n < 4; ++n)
#pragma unroll
      for (int j = 0; j < 4; ++j) acc[m][n][j] = 0.f;

  int lr = l & 15, kg = l >> 4;

  for (int ks = 0; ks < 32; ++ks) {          // K = 2048 = 32 * 64
#pragma unroll
    for (int i = 0; i < 4; ++i) {
      int g = i * 4 + w;
      int r = g * 8 + sr;
      int cl = sc ^ (r & 7);
      size_t goff = (size_t)r * (DM * 2) + (size_t)ks * 128 + (size_t)cl * 16;
      gld16(gA + goff, lA + g * 1024);
      gld16(gB + goff, lB + g * 1024);
    }
    __syncthreads();
#pragma unroll
    for (int kk = 0; kk < 2; ++kk) {
      int chunk = kk * 4 + kg;
      bf16x8 af[4], bf[4];
#pragma unroll
      for (int m = 0; m < 4; ++m) {
        int r = wr * 64 + m * 16 + lr;
        af[m] = *(const bf16x8*)(lA + r * 128 + ((chunk ^ (r & 7)) * 16));
      }
#pragma unroll
      for (int n = 0; n < 4; ++n) {
        int r = wc * 64 + n * 16 + lr;
        bf[n] = *(const bf16x8*)(lB + r * 128 + ((chunk ^ (r & 7)) * 16));
      }
#pragma unroll
      for (int m = 0; m < 4; ++m)
#pragma unroll
        for (int n = 0; n < 4; ++n)
          acc[m][n] = __builtin_amdgcn_mfma_f32_16x16x32_bf16(af[m], bf[n],
                                                              acc[m][n], 0, 0, 0);
    }
    __syncthreads();
  }

  // ---- epilogue: C/D layout col=lane&15, row=(lane>>4)*4+j [m89-verified]
  int rg = l >> 4;
#pragma unroll
  for (int m = 0; m < 4; ++m)
#pragma unroll
    for (int n = 0; n < 4; ++n)
#pragma unroll
      for (int j = 0; j < 4; ++j) {
        int rr = row0 + wr * 64 + m * 16 + rg * 4 + j;
        int cc = nt * 128 + wc * 64 + n * 16 + lr;
        size_t off = (size_t)rr * DM + cc;
        float v = acc[m][n][j];
        if constexpr (SWI) {
          float u = (float)U[off];
          float s = u / (1.f + __expf(-u));
          C[off] = (__bf16)(s * v);            // h = silu(u) * v, in place
        } else {
          C[off] = (__bf16)v;
        }
      }
}

// --------------------------------------------- combine: y[tok] = sum w * ye
__global__ void combine_k(const __bf16* __restrict__ ye, const int* __restrict__ slot_dest,
                          const float* __restrict__ ew, float* __restrict__ out) {
  int tok = blockIdx.x;
  int c = threadIdx.x * 8;
  int d0 = slot_dest[2 * tok], d1 = slot_dest[2 * tok + 1];
  float w0 = ew[2 * tok], w1 = ew[2 * tok + 1];
  float r[8];
#pragma unroll
  for (int j = 0; j < 8; ++j) r[j] = 0.f;
  if (d0 >= 0) {
    bf16x8 y0 = *(const bf16x8*)(ye + (size_t)d0 * DM + c);
#pragma unroll
    for (int j = 0; j < 8; ++j) r[j] += w0 * (float)y0[j];
  }
  if (d1 >= 0) {
    bf16x8 y1 = *(const bf16x8*)(ye + (size_t)d1 * DM + c);
#pragma unroll
    for (int j = 0; j < 8; ++j) r[j] += w1 * (float)y1[j];
  }
  float* dst = out + (size_t)tok * DM + c;
  float4 o0; o0.x = r[0]; o0.y = r[1]; o0.z = r[2]; o0.w = r[3];
  float4 o1; o1.x = r[4]; o1.y = r[5]; o1.z = r[6]; o1.w = r[7];
  *(float4*)dst = o0;
  *(float4*)(dst + 4) = o1;
}

extern "C" void kernel_launch(void* const* d_in, const int* in_sizes, int n_in,
                              void* d_out, int out_size, void* d_ws, size_t ws_size,
                              hipStream_t stream) {
  const float* x  = (const float*)d_in[0];
  const float* ew = (const float*)d_in[1];
  const int*   ei = (const int*)d_in[2];
  const float* w1 = (const float*)d_in[3];
  const float* w2 = (const float*)d_in[4];
  const float* w3 = (const float*)d_in[5];
  float* out = (float*)d_out;
  char* ws = (char*)d_ws;

  const size_t SZ_MAT = (size_t)EC * DM * 2;            // 41,943,040 B
  __bf16* xg = (__bf16*)ws;                             // xg, then ye
  __bf16* uB = (__bf16*)(ws + SZ_MAT);                  // u, then h
  __bf16* wT = (__bf16*)(ws + 2 * SZ_MAT);              // [8][2048][2048] bf16
  char* ints = ws + 2 * SZ_MAT + (size_t)NEXP * DM * DM * 2;
  int* row_token = (int*)ints;
  int* slot_dest = row_token + EC;
  int* mcount    = slot_dest + NSLOT;

  dim3 tgrid(32, 32, NEXP);
  dim3 ggrid(16, 10, NEXP);                             // nt(128), mt(128), e

  route_k<<<1, 256, 0, stream>>>(ei, row_token, slot_dest, mcount, out);
  gather_k<<<EC, 256, 0, stream>>>(x, row_token, xg);

  transT_k<<<tgrid, 256, 0, stream>>>(w1, wT);
  gemm_k<false><<<ggrid, 256, 0, stream>>>(xg, wT, uB, nullptr, mcount); // u

  transT_k<<<tgrid, 256, 0, stream>>>(w3, wT);
  gemm_k<true><<<ggrid, 256, 0, stream>>>(xg, wT, uB, uB, mcount);       // h

  transT_k<<<tgrid, 256, 0, stream>>>(w2, wT);
  gemm_k<false><<<ggrid, 256, 0, stream>>>(uB, wT, xg, nullptr, mcount); // ye

  combine_k<<<NTOK, 256, 0, stream>>>(xg, slot_dest, ew, out);
}

// Round 7
// 349.360 us; speedup vs baseline: 1.6604x; 1.2856x over previous
//
#include <hip/hip_runtime.h>
#include <cstdint>

#define NEXP 8
#define TOPK 2
#define NTOK 4096
#define NSLOT (NTOK * TOPK)   // 8192
#define CAP 1280              // expert capacity
#define DM 2048               // d_model == hidden
#define EC (NEXP * CAP)       // 10240 binned rows

typedef __bf16 bf16x8 __attribute__((ext_vector_type(8)));
typedef float  f32x4  __attribute__((ext_vector_type(4)));

typedef const void __attribute__((address_space(1))) gvoid;
typedef void __attribute__((address_space(3))) lvoid;

__device__ __forceinline__ void gld16(const void* g, void* l) {
  __builtin_amdgcn_global_load_lds((gvoid*)(uintptr_t)g, (lvoid*)(uintptr_t)l,
                                   16, 0, 0);
}

// pack 4 f32 -> 4 fp8 e4m3 bytes (OCP on gfx950)
__device__ __forceinline__ unsigned fp8x4(float a, float b, float c, float d) {
  int v = __builtin_amdgcn_cvt_pk_fp8_f32(a, b, 0, false);
  v = __builtin_amdgcn_cvt_pk_fp8_f32(c, d, v, true);
  return (unsigned)v;
}
__device__ __forceinline__ unsigned char fp8１(float a) {
  return (unsigned char)(__builtin_amdgcn_cvt_pk_fp8_f32(a, a, 0, false) & 0xff);
}

// ---------------------------------------------------------------- routing
__global__ void route_k(const int* __restrict__ eidx, int* __restrict__ row_token,
                        int* __restrict__ slot_dest, int* __restrict__ mcount,
                        float* __restrict__ out) {
  __shared__ int lh[256][NEXP];
  int tid = threadIdx.x;
  for (int i = tid; i < EC; i += 256) row_token[i] = -1;
#pragma unroll
  for (int e = 0; e < NEXP; ++e) lh[tid][e] = 0;
  __syncthreads();
  int base = tid * 32;
  for (int j = 0; j < 32; ++j) lh[tid][eidx[base + j]]++;
  __syncthreads();
  if (tid < NEXP) {
    int run = 0;
    for (int i = 0; i < 256; ++i) { int t = lh[i][tid]; lh[i][tid] = run; run += t; }
    mcount[tid] = run < CAP ? run : CAP;
    out[(size_t)NTOK * DM + tid] = (float)run;
  }
  __syncthreads();
  for (int j = 0; j < 32; ++j) {
    int t = base + j;
    int e = eidx[t];
    int r = lh[tid][e]++;
    if (r < CAP) { int dst = e * CAP + r; slot_dest[t] = dst; row_token[dst] = t >> 1; }
    else slot_dest[t] = -1;
  }
}

// ------------------------------------------------------- gather + fp32->fp8
__global__ void gather_k(const float* __restrict__ x, const int* __restrict__ row_token,
                         unsigned char* __restrict__ xg) {
  int r = blockIdx.x;
  int c = threadIdx.x * 8;
  int tok = row_token[r];
  uint2 o;
  if (tok >= 0) {
    const float* src = x + (size_t)tok * DM + c;
    float4 a = *(const float4*)src;
    float4 b = *(const float4*)(src + 4);
    o.x = fp8x4(a.x, a.y, a.z, a.w);
    o.y = fp8x4(b.x, b.y, b.z, b.w);
  } else {
    o.x = 0u; o.y = 0u;
  }
  *(uint2*)(xg + (size_t)r * DM + c) = o;
}

// --------------------------------------- fp32 [E][K][N] -> fp8 [E][N][K]
__global__ void transT_k(const float* __restrict__ w, unsigned char* __restrict__ wT) {
  __shared__ float t[64][65];
  int e = blockIdx.z;
  int n0 = blockIdx.x * 64, k0 = blockIdx.y * 64;
  const float* src = w + ((size_t)e << 22) + (size_t)k0 * DM + n0;
  unsigned char* dst = wT + ((size_t)e << 22) + (size_t)n0 * DM + k0;
  int c = threadIdx.x & 63, r4 = threadIdx.x >> 6;
#pragma unroll
  for (int p = 0; p < 16; ++p) {
    int r = p * 4 + r4;
    t[r][c] = src[(size_t)r * DM + c];
  }
  __syncthreads();
  int j = threadIdx.x & 15, rr0 = threadIdx.x >> 4;
#pragma unroll
  for (int q = 0; q < 4; ++q) {
    int rr = q * 16 + rr0;
    unsigned v = fp8x4(t[4 * j + 0][rr], t[4 * j + 1][rr],
                       t[4 * j + 2][rr], t[4 * j + 3][rr]);
    *(unsigned*)(dst + (size_t)rr * DM + 4 * j) = v;   // 4B coalesced stores
  }
}

// ------------------------------------------------------------------- GEMM
// fp8 e4m3 version of the R1-proven structure: 128x128 tile, BK=128 (rows =
// 128B fp8 -> R1's zero-conflict chunk^(r&7) swizzle), 4 waves (2x2), single
// LDS buffer (32KB), 2 syncthreads per K-tile (16 iters: barrier count halved
// vs bf16-BK64). MFMA 16x16x32_fp8_fp8 (K-mapping same as bf16 16x16x32:
// row=lane&15, k=(lane>>4)*8+i, verified structure). b64 frag reads: per row
// 4 lanes cover 2 full 16B chunks; rows r,r+8 alias -> 2 lanes/bank = free
// (m136). Staged with inverse-swizzled GLOBAL source + linear LDS dest
// (rule #21). XCD-chunked swizzle kept (R5/R6: FETCH 197->86/118MB).
template<bool SWI>
__global__ __launch_bounds__(256, 2)
void gemm_k(const unsigned char* __restrict__ A0, const unsigned char* __restrict__ BT,
            void* C, const __bf16* __restrict__ U, const int* __restrict__ mcount) {
  int lbid = blockIdx.x + 16 * (blockIdx.y + 10 * blockIdx.z);
  int nb = (lbid & 7) * 160 + (lbid >> 3);
  int e = nb / 160, rem = nb % 160, mt = rem >> 4, nt = rem & 15;
  int mc = mcount[e];
  if (mt * 128 >= mc) return;

  __shared__ __align__(16) char smem[32 * 1024];   // A 16KB + B 16KB
  char* lA = smem;
  char* lB = smem + 16384;

  int row0 = e * CAP + mt * 128;
  const unsigned char* gA = A0 + (size_t)row0 * DM;
  const unsigned char* gB = BT + ((size_t)e * DM + (size_t)nt * 128) * DM;

  int tid = threadIdx.x, w = tid >> 6, l = tid & 63;
  int wr = w >> 1, wc = w & 1;
  int lr = l & 15, kg = l >> 4;

  int sr = tid >> 3;                 // staging row-in-call (0..31)
  int scs = (tid & 7) ^ (sr & 7);    // inverse-swizzled source chunk

  f32x4 acc[4][4];
#pragma unroll
  for (int m = 0; m < 4; ++m)
#pragma unroll
    for (int n = 0; n < 4; ++n)
#pragma unroll
      for (int j = 0; j < 4; ++j) acc[m][n][j] = 0.f;

  for (int ks = 0; ks < 16; ++ks) {          // K = 2048 = 16 * 128
    // ---- stage A and B tiles: 128 rows x 128B each; 4 calls/tile
    //      (call cs: rows cs*32..cs*32+31; 256 lanes x 16B = 4KB linear LDS)
#pragma unroll
    for (int cs = 0; cs < 4; ++cs) {
      size_t goff = (size_t)(cs * 32 + sr) * DM + (size_t)ks * 128 + scs * 16;
      gld16(gA + goff, lA + cs * 4096 + w * 1024);
      gld16(gB + goff, lB + cs * 4096 + w * 1024);
    }
    __syncthreads();
    // ---- 4 K-slabs of 32: 8 b64 frag reads + 16 MFMA each
#pragma unroll
    for (int kk = 0; kk < 4; ++kk) {
      int chunk = kk * 2 + (kg >> 1);
      int ho = (kg & 1) << 3;
      long af[4], bf[4];
#pragma unroll
      for (int m = 0; m < 4; ++m) {
        int r = wr * 64 + m * 16 + lr;
        af[m] = *(const long*)(lA + r * 128 + ((chunk ^ (r & 7)) << 4) + ho);
      }
#pragma unroll
      for (int n = 0; n < 4; ++n) {
        int r = wc * 64 + n * 16 + lr;
        bf[n] = *(const long*)(lB + r * 128 + ((chunk ^ (r & 7)) << 4) + ho);
      }
#pragma unroll
      for (int m = 0; m < 4; ++m)
#pragma unroll
        for (int n = 0; n < 4; ++n)
          acc[m][n] = __builtin_amdgcn_mfma_f32_16x16x32_fp8_fp8(af[m], bf[n],
                                                                 acc[m][n], 0, 0, 0);
    }
    __syncthreads();
  }

  // ---- epilogue: C/D layout col=lane&15, row=(lane>>4)*4+j [m89-verified]
  int rg = l >> 4;
#pragma unroll
  for (int m = 0; m < 4; ++m)
#pragma unroll
    for (int n = 0; n < 4; ++n)
#pragma unroll
      for (int j = 0; j < 4; ++j) {
        int rr = row0 + wr * 64 + m * 16 + rg * 4 + j;
        int cc = nt * 128 + wc * 64 + n * 16 + lr;
        size_t off = (size_t)rr * DM + cc;
        float v = acc[m][n][j];
        if constexpr (SWI) {
          float u = (float)U[off];
          float s = u / (1.f + __expf(-u));
          ((unsigned char*)C)[off] = fp8１(s * v);   // h = silu(u)*v, fp8
        } else {
          ((__bf16*)C)[off] = (__bf16)v;
        }
      }
}

// --------------------------------------------- combine: y[tok] = sum w * ye
__global__ void combine_k(const __bf16* __restrict__ ye, const int* __restrict__ slot_dest,
                          const float* __restrict__ ew, float* __restrict__ out) {
  int tok = blockIdx.x;
  int c = threadIdx.x * 8;
  int d0 = slot_dest[2 * tok], d1 = slot_dest[2 * tok + 1];
  float w0 = ew[2 * tok], w1 = ew[2 * tok + 1];
  float r[8];
#pragma unroll
  for (int j = 0; j < 8; ++j) r[j] = 0.f;
  if (d0 >= 0) {
    bf16x8 y0 = *(const bf16x8*)(ye + (size_t)d0 * DM + c);
#pragma unroll
    for (int j = 0; j < 8; ++j) r[j] += w0 * (float)y0[j];
  }
  if (d1 >= 0) {
    bf16x8 y1 = *(const bf16x8*)(ye + (size_t)d1 * DM + c);
#pragma unroll
    for (int j = 0; j < 8; ++j) r[j] += w1 * (float)y1[j];
  }
  float* dst = out + (size_t)tok * DM + c;
  float4 o0; o0.x = r[0]; o0.y = r[1]; o0.z = r[2]; o0.w = r[3];
  float4 o1; o1.x = r[4]; o1.y = r[5]; o1.z = r[6]; o1.w = r[7];
  *(float4*)dst = o0;
  *(float4*)(dst + 4) = o1;
}

extern "C" void kernel_launch(void* const* d_in, const int* in_sizes, int n_in,
                              void* d_out, int out_size, void* d_ws, size_t ws_size,
                              hipStream_t stream) {
  const float* x  = (const float*)d_in[0];
  const float* ew = (const float*)d_in[1];
  const int*   ei = (const int*)d_in[2];
  const float* w1 = (const float*)d_in[3];
  const float* w2 = (const float*)d_in[4];
  const float* w3 = (const float*)d_in[5];
  float* out = (float*)d_out;
  char* ws = (char*)d_ws;

  // ws: xg fp8 (21MB) | uB bf16 (42MB: u, then ye) | hB fp8 (21MB) |
  //     wT fp8 (33.5MB, reused 3x) | routing ints       (~118MB total)
  const size_t SZ8  = (size_t)EC * DM;                  // 20,971,520
  const size_t SZ16 = 2 * SZ8;                          // 41,943,040
  unsigned char* xg = (unsigned char*)ws;
  __bf16* uB = (__bf16*)(ws + SZ8);                     // u, then ye
  unsigned char* hB = (unsigned char*)(ws + SZ8 + SZ16);
  unsigned char* wT = (unsigned char*)(ws + 2 * SZ8 + SZ16);
  char* ints = ws + 2 * SZ8 + SZ16 + (size_t)NEXP * DM * DM;
  int* row_token = (int*)ints;
  int* slot_dest = row_token + EC;
  int* mcount    = slot_dest + NSLOT;

  dim3 tgrid(32, 32, NEXP);
  dim3 ggrid(16, 10, NEXP);                             // nt(128), mt(128), e

  route_k<<<1, 256, 0, stream>>>(ei, row_token, slot_dest, mcount, out);
  gather_k<<<EC, 256, 0, stream>>>(x, row_token, xg);

  transT_k<<<tgrid, 256, 0, stream>>>(w1, wT);
  gemm_k<false><<<ggrid, 256, 0, stream>>>(xg, wT, uB, nullptr, mcount); // u (bf16)

  transT_k<<<tgrid, 256, 0, stream>>>(w3, wT);
  gemm_k<true><<<ggrid, 256, 0, stream>>>(xg, wT, hB, uB, mcount);       // h (fp8)

  transT_k<<<tgrid, 256, 0, stream>>>(w2, wT);
  gemm_k<false><<<ggrid, 256, 0, stream>>>(hB, wT, uB, nullptr, mcount); // ye (bf16)

  combine_k<<<NTOK, 256, 0, stream>>>(uB, slot_dest, ew, out);
}